// Round 9
// baseline (138.834 us; speedup 1.0000x reference)
//
#include <hip/hip_runtime.h>
#include <math.h>

// Fused soft-argmax centroid over [B,K,128,128] fp32, two inputs.
// NT (nontemporal) loads + 2-way unit split:
//   Stage 1: 4096 blocks x 256 threads; each block = half a unit (64 rows,
//            32 KB), 8 NT float4 per thread -> partials {s, sx, sy} in d_ws.
//   Stage 2: one thread per unit combines 2 partials, divides, rounds.

#define HM_H 128
#define HM_W 128
#define PARTS 2

typedef float vf4 __attribute__((ext_vector_type(4)));

__global__ __launch_bounds__(256) void centroid_nt2(
    const float* __restrict__ hm0,
    const float* __restrict__ hm1,
    float* __restrict__ ws,
    int BK)
{
    const int gb   = blockIdx.x;            // 0 .. 2*BK*PARTS-1
    const int part = gb & (PARTS - 1);
    const int u    = gb >> 1;               // unit 0 .. 2*BK-1
    const int bk   = (u >= BK) ? (u - BK) : u;
    const vf4* __restrict__ p =
        (const vf4*)(((u >= BK) ? hm1 : hm0) + (size_t)bk * (HM_H * HM_W))
        + part * (PARTS == 2 ? 2048 : 0);
    const int t = threadIdx.x;

    const float colb = (float)((t << 2) & (HM_W - 1)); // column of lane's 4-group
    const float rowb = (float)(t >> 5);                // row of chunk m = rowb+8m

    float s = 0.0f, sx = 0.0f, sy = 0.0f;

#pragma unroll
    for (int m = 0; m < 8; ++m) {
        const vf4 v = __builtin_nontemporal_load(&p[t + m * 256]);
        const float sv = (v[0] + v[1]) + (v[2] + v[3]);
        s  += sv;
        sx += (v[1] + 2.0f * v[2]) + 3.0f * v[3];
        sy += (float)(8 * m) * sv;          // local row = rowb + 8m
    }
    sx += colb * s;
    sy += (rowb + (float)(64 * part)) * s;  // global row offset for this half

    // ---- wave (64-lane) butterfly reduce ----
#pragma unroll
    for (int off = 32; off > 0; off >>= 1) {
        s  += __shfl_down(s,  off, 64);
        sx += __shfl_down(sx, off, 64);
        sy += __shfl_down(sy, off, 64);
    }

    __shared__ float ls[4], lx[4], ly[4];
    const int wid  = t >> 6;
    const int lane = t & 63;
    if (lane == 0) { ls[wid] = s; lx[wid] = sx; ly[wid] = sy; }
    __syncthreads();

    if (t == 0) {
        ws[gb * 3 + 0] = ls[0] + ls[1] + ls[2] + ls[3];
        ws[gb * 3 + 1] = lx[0] + lx[1] + lx[2] + lx[3];
        ws[gb * 3 + 2] = ly[0] + ly[1] + ly[2] + ly[3];
    }
}

__global__ __launch_bounds__(256) void centroid_nt2_final(
    const float* __restrict__ ws,
    float* __restrict__ out,
    int nunits)
{
    const int u = blockIdx.x * 256 + threadIdx.x;
    if (u >= nunits) return;
    const float* __restrict__ w = ws + (size_t)u * (PARTS * 3);
    float S = 0.0f, X = 0.0f, Y = 0.0f;
#pragma unroll
    for (int pr = 0; pr < PARTS; ++pr) {
        S += w[pr * 3 + 0];
        X += w[pr * 3 + 1];
        Y += w[pr * 3 + 2];
    }
    // out = [keypoint (BK*2) | tf_keypoint (BK*2)]
    out[u * 2 + 0] = rintf(X / S);   // round-half-to-even == jnp.round
    out[u * 2 + 1] = rintf(Y / S);
}

extern "C" void kernel_launch(void* const* d_in, const int* in_sizes, int n_in,
                              void* d_out, int out_size, void* d_ws, size_t ws_size,
                              hipStream_t stream) {
    const float* hm0 = (const float*)d_in[0];
    const float* hm1 = (const float*)d_in[1];
    float* out = (float*)d_out;
    float* ws  = (float*)d_ws;

    const int BK     = out_size / 4;     // B*K
    const int nunits = 2 * BK;           // 2048
    const int grid1  = nunits * PARTS;   // 4096 stage-1 blocks

    centroid_nt2<<<grid1, 256, 0, stream>>>(hm0, hm1, ws, BK);
    centroid_nt2_final<<<(nunits + 255) / 256, 256, 0, stream>>>(ws, out, nunits);
}